// Round 4
// baseline (436.332 us; speedup 1.0000x reference)
//
#include <hip/hip_runtime.h>

// ---------- problem constants ----------
#define CDIM   768
#define NSEQ   196
#define NVIEW  5
#define BN_TOT 6272       // B*N
#define SLAB   4816896    // BN_TOT*CDIM
#define WSLAB  589824     // CDIM*CDIM

typedef __attribute__((ext_vector_type(8))) short short8;  // 8 bf16 (4 VGPRs)
typedef __attribute__((ext_vector_type(4))) float f32x4;

// ---------- helpers ----------
__device__ __forceinline__ float bf_lo(unsigned u) { return __uint_as_float(u << 16); }
__device__ __forceinline__ float bf_hi(unsigned u) { return __uint_as_float(u & 0xffff0000u); }
__device__ __forceinline__ unsigned short f2bf(float f) {
  unsigned u = __float_as_uint(f);
  return (unsigned short)((u + 0x7fffu + ((u >> 16) & 1u)) >> 16);  // RNE
}
__device__ __forceinline__ unsigned pack2(float f0, float f1) {
  return (unsigned)f2bf(f0) | ((unsigned)f2bf(f1) << 16);
}
__device__ __forceinline__ float ftanh(float x) {
  x = fminf(fmaxf(x, -10.f), 10.f);
  float e = __expf(2.f * x);
  return (e - 1.f) / (e + 1.f);
}
__device__ __forceinline__ void async_cp16(const void* g, void* l) {
  __builtin_amdgcn_global_load_lds((const __attribute__((address_space(1))) unsigned*)g,
                                   (__attribute__((address_space(3))) unsigned*)l, 16, 0, 0);
}

// ---------- launch 1: weight transposes (z<7) + mean over views (z==7) ----------
// z<7: fp32->bf16 transposes of 7 768x768 mats (+ plain bf16 wv copy).
// z==7: cb[bn][c] = bf16(mean_v x) — 576 blocks x 11 bn, threads 0..191 do 4 cols.
__global__ __launch_bounds__(256) void k_tr2(const float* __restrict__ wv,
                                             const float* __restrict__ w1,
                                             const float* __restrict__ x,
                                             unsigned short* __restrict__ wvT,
                                             unsigned short* __restrict__ w1aT,
                                             unsigned short* __restrict__ w1bT,
                                             unsigned short* __restrict__ wvB,
                                             unsigned short* __restrict__ cb) {
  const int m = blockIdx.z;
  const int tx = threadIdx.x, ty = threadIdx.y, t = ty * 32 + tx;
  if (m == 7) {               // ---- mean works ----
    const int bidx = blockIdx.y * 24 + blockIdx.x;   // 0..575
    if (t < 192) {
      const int col = t * 4;
      for (int i = 0; i < 11; ++i) {
        const int bn = bidx * 11 + i;
        if (bn >= BN_TOT) break;
        const int b = bn / NSEQ, n = bn - b * NSEQ;
        const float* xp = x + ((size_t)(b * NVIEW) * NSEQ + n) * CDIM + col;
        float s0 = 0, s1 = 0, s2 = 0, s3 = 0;
#pragma unroll
        for (int v = 0; v < NVIEW; ++v) {
          float4 p = *(const float4*)(xp + (size_t)v * (NSEQ * CDIM));
          s0 += p.x; s1 += p.y; s2 += p.z; s3 += p.w;
        }
        uint2 o;
        o.x = pack2(s0 * 0.2f, s1 * 0.2f);
        o.y = pack2(s2 * 0.2f, s3 * 0.2f);
        *(uint2*)(cb + (size_t)bn * CDIM + col) = o;
      }
    }
    return;
  }
  __shared__ float tile[32][33];
  const float* src;
  unsigned short* dst;
  unsigned short* dstB = nullptr;
  if (m < NVIEW)      { src = wv + (size_t)m * WSLAB; dst = wvT + (size_t)m * WSLAB;
                        dstB = wvB + (size_t)m * WSLAB; }
  else if (m == NVIEW){ src = w1;                     dst = w1aT; }
  else                { src = w1 + WSLAB;             dst = w1bT; }
  const int x0 = blockIdx.x * 32, y0 = blockIdx.y * 32;
#pragma unroll
  for (int i = 0; i < 4; ++i) {
    float v = src[(size_t)(y0 + ty + i * 8) * CDIM + x0 + tx];
    tile[ty + i * 8][tx] = v;
    if (dstB) dstB[(size_t)(y0 + ty + i * 8) * CDIM + x0 + tx] = f2bf(v);
  }
  __syncthreads();
#pragma unroll
  for (int i = 0; i < 4; ++i)
    dst[(size_t)(x0 + ty + i * 8) * CDIM + y0 + tx] = f2bf(tile[tx][ty + i * 8]);
}

// ---------- launch 2: small GEMMs, merged (no solo small-grid walls) ----------
// works 0..179:   wpT_v = w1bT @ wvB_v^T   (M=768, i.e. (wv@w1b)^T)
// works 180..473: cw1   = cb @ w1bT        (M=6272)
// 128x128 tile, 4 waves 2mx2n (64x64 each), BK=32, dbuf 32KiB LDS, bf16-DMA A.
// XOR swizzle (chunk ^= (row>>1)&3) on pre-swizzled global source + ds_read addr.
__global__ __launch_bounds__(256, 4) void k_pre(const unsigned short* __restrict__ w1bT,
                                                const unsigned short* __restrict__ wvB,
                                                const unsigned short* __restrict__ cb,
                                                unsigned short* __restrict__ wpT,
                                                unsigned short* __restrict__ cw1) {
  __shared__ __align__(16) unsigned short lds[16384];   // 2 slots x (A 4096 + B 4096)
  const int wk = blockIdx.x;
  const int t = threadIdx.x, w = t >> 6, lane = t & 63, lr = lane & 15, lq = lane >> 4;
  const int wm = (w >> 1) * 64, wn = (w & 1) * 64;
  const unsigned short *Abf, *Bt;
  unsigned short* C;
  int mrow0, colBase;
  if (wk < 180) {
    const int v = wk / 36, rem = wk % 36;
    mrow0 = (rem / 6) * 128; colBase = (rem % 6) * 128;
    Abf = w1bT; Bt = wvB + (size_t)v * WSLAB; C = wpT + (size_t)v * WSLAB;
  } else {
    const int j = wk - 180;
    mrow0 = (j / 6) * 128; colBase = (j % 6) * 128;
    Abf = cb; Bt = w1bT; C = cw1;
  }
  const int swz = ((t & 3) ^ ((t >> 3) & 3)) << 3;
  const unsigned short* gA = Abf + (size_t)(mrow0 + (t >> 2)) * CDIM + swz;
  const unsigned short* gB = Bt + (size_t)(colBase + (t >> 2)) * CDIM + swz;
  const int kch = ((lq ^ ((lr >> 1) & 3)) << 3);
#define CPA(kt, s) { unsigned short* d_ = lds + (s) * 8192 + (w << 9);                  \
    async_cp16(gA + (kt) * 32, d_);                                                     \
    async_cp16(gA + (kt) * 32 + (size_t)64 * CDIM, d_ + 2048); }
#define CPB(kt, s) { unsigned short* d_ = lds + (s) * 8192 + 4096 + (w << 9);           \
    async_cp16(gB + (kt) * 32, d_);                                                     \
    async_cp16(gB + (kt) * 32 + (size_t)64 * CDIM, d_ + 2048); }
  f32x4 acc[4][4] = {};
  CPA(0, 0); CPB(0, 0);
  asm volatile("s_waitcnt vmcnt(0)" ::: "memory");
  __builtin_amdgcn_s_barrier();
  for (int kt = 0; kt < 24; ++kt) {
    const int s = kt & 1;
    const unsigned short* bp = lds + s * 8192;
    if (kt < 23) { CPA(kt + 1, s ^ 1); CPB(kt + 1, s ^ 1); }
    short8 af[4], bf[4];
#pragma unroll
    for (int i = 0; i < 4; ++i) af[i] = *(const short8*)(bp + (wm + i * 16 + lr) * 32 + kch);
#pragma unroll
    for (int j = 0; j < 4; ++j) bf[j] = *(const short8*)(bp + 4096 + (wn + j * 16 + lr) * 32 + kch);
    __builtin_amdgcn_s_setprio(1);
#pragma unroll
    for (int i = 0; i < 4; ++i)
#pragma unroll
      for (int j = 0; j < 4; ++j)
        acc[i][j] = __builtin_amdgcn_mfma_f32_16x16x32_bf16(af[i], bf[j], acc[i][j], 0, 0, 0);
    __builtin_amdgcn_s_setprio(0);
    asm volatile("s_waitcnt vmcnt(0) lgkmcnt(0)" ::: "memory");
    __builtin_amdgcn_s_barrier();
  }
#undef CPA
#undef CPB
#pragma unroll
  for (int i = 0; i < 4; ++i)
#pragma unroll
    for (int j = 0; j < 4; ++j) {
      const int gr = mrow0 + wm + i * 16 + lq * 4;
      const int gc = colBase + wn + j * 16 + lr;
      unsigned short* cp = C + (size_t)gr * CDIM + gc;
#pragma unroll
      for (int r = 0; r < 4; ++r)
        cp[(size_t)r * CDIM] = f2bf(acc[i][j][r]);
    }
}

// ---------- launch 3: main GEMM, mode-0 only (proj | xw1 | pw1b), 4 blocks/CU ----------
// 4410 works = 5v x 49mt x 18(3 mats x 6 nt). 128x128 tile, 4 waves 2mx2n,
// BK=32, dbuf 32KiB LDS, regs ~64 VGPR + 64 acc-AGPR = 4 blocks/CU target.
// A = x fp32 loaded to regs, packed bf16, ds_written post-MFMA (write-side swizzle).
// B = bf16 weights via global_load_lds (pre-swizzled source). 18 consecutive
// works share A-rows; XCD swizzle keeps them on one L2.
__global__ __launch_bounds__(256, 4) void gemm_m(const float* __restrict__ X,
                                                 const unsigned short* __restrict__ wvT,
                                                 const unsigned short* __restrict__ w1aT,
                                                 const unsigned short* __restrict__ wpT,
                                                 unsigned short* __restrict__ projb,
                                                 unsigned short* __restrict__ xw1b,
                                                 unsigned short* __restrict__ pw1b) {
  __shared__ __align__(16) unsigned short lds[16384];
  // bijective XCD swizzle: 4410 = 8*551 + 2
  const int orig = blockIdx.x;
  const int xcd = orig & 7, slot0 = orig >> 3;
  const int wk = (xcd < 2 ? xcd * 552 : 1104 + (xcd - 2) * 551) + slot0;
  const int t = threadIdx.x, w = t >> 6, lane = t & 63, lr = lane & 15, lq = lane >> 4;
  const int wm = (w >> 1) * 64, wn = (w & 1) * 64;
  const int v = wk / 882, rem = wk % 882;
  const int mt = rem / 18, qq = rem % 18, sub = qq / 6;
  const int colBase = (qq % 6) * 128, mrow0 = mt * 128;
  const unsigned short* Bt = sub == 0 ? wvT + (size_t)v * WSLAB
                            : sub == 1 ? w1aT : wpT + (size_t)v * WSLAB;
  unsigned short* C = (sub == 0 ? projb : sub == 1 ? xw1b : pw1b) + (size_t)v * SLAB;
  const int r = mrow0 + (t >> 1), b = r / NSEQ, n = r - b * NSEQ;
  const float* aRow = X + ((size_t)((b * NVIEW + v) * NSEQ) + n) * CDIM + (t & 1) * 16;
  const int swz = ((t & 3) ^ ((t >> 3) & 3)) << 3;
  const unsigned short* gB = Bt + (size_t)(colBase + (t >> 2)) * CDIM + swz;
  const int sw = (t >> 2) & 3, c0 = (t & 1) * 2;
  const int wA0 = (t >> 1) * 32 + ((c0 ^ sw) << 3);
  const int wA1 = (t >> 1) * 32 + (((c0 + 1) ^ sw) << 3);
  const int kch = ((lq ^ ((lr >> 1) & 3)) << 3);
#define CPB(kt, s) { unsigned short* d_ = lds + (s) * 8192 + 4096 + (w << 9);           \
    async_cp16(gB + (kt) * 32, d_);                                                     \
    async_cp16(gB + (kt) * 32 + (size_t)64 * CDIM, d_ + 2048); }
#define LOADA(kt) { f0 = *(const float4*)(aRow + (kt) * 32);                            \
    f1 = *(const float4*)(aRow + (kt) * 32 + 4);                                        \
    f2 = *(const float4*)(aRow + (kt) * 32 + 8);                                        \
    f3 = *(const float4*)(aRow + (kt) * 32 + 12); }
#define PACKW(s) { uint4 u0, u1;                                                        \
    u0.x = pack2(f0.x, f0.y); u0.y = pack2(f0.z, f0.w);                                 \
    u0.z = pack2(f1.x, f1.y); u0.w = pack2(f1.z, f1.w);                                 \
    u1.x = pack2(f2.x, f2.y); u1.y = pack2(f2.z, f2.w);                                 \
    u1.z = pack2(f3.x, f3.y); u1.w = pack2(f3.z, f3.w);                                 \
    *(uint4*)(lds + (s) * 8192 + wA0) = u0;                                             \
    *(uint4*)(lds + (s) * 8192 + wA1) = u1; }
  f32x4 acc[4][4] = {};
  float4 f0, f1, f2, f3;
  LOADA(0); CPB(0, 0); PACKW(0);
  asm volatile("s_waitcnt vmcnt(0) lgkmcnt(0)" ::: "memory");
  __builtin_amdgcn_s_barrier();
  for (int kt = 0; kt < 24; ++kt) {
    const int s = kt & 1;
    const unsigned short* bp = lds + s * 8192;
    const bool pf = (kt < 23);
    if (pf) { LOADA(kt + 1); CPB(kt + 1, s ^ 1); }   // fly during MFMA
    short8 af[4], bf[4];
#pragma unroll
    for (int i = 0; i < 4; ++i) af[i] = *(const short8*)(bp + (wm + i * 16 + lr) * 32 + kch);
#pragma unroll
    for (int j = 0; j < 4; ++j) bf[j] = *(const short8*)(bp + 4096 + (wn + j * 16 + lr) * 32 + kch);
    __builtin_amdgcn_s_setprio(1);
#pragma unroll
    for (int i = 0; i < 4; ++i)
#pragma unroll
      for (int j = 0; j < 4; ++j)
        acc[i][j] = __builtin_amdgcn_mfma_f32_16x16x32_bf16(af[i], bf[j], acc[i][j], 0, 0, 0);
    __builtin_amdgcn_s_setprio(0);
    if (pf) PACKW(s ^ 1);                            // loads had the MFMA window to land
    asm volatile("s_waitcnt vmcnt(0) lgkmcnt(0)" ::: "memory");
    __builtin_amdgcn_s_barrier();
  }
#undef CPB
#undef LOADA
#undef PACKW
#pragma unroll
  for (int i = 0; i < 4; ++i)
#pragma unroll
    for (int j = 0; j < 4; ++j) {
      const int gr = mrow0 + wm + i * 16 + lq * 4;   // C/D: row=(lane>>4)*4+reg, col=lane&15
      const int gc = colBase + wn + j * 16 + lr;
      unsigned short* cp = C + (size_t)gr * CDIM + gc;
#pragma unroll
      for (int rr = 0; rr < 4; ++rr)
        cp[(size_t)rr * CDIM] = f2bf(acc[i][j][rr]);
    }
}

// ---------- fully fused routing loop: 3x (scores -> softmax -> weighted sum), pointwise in bn ----------
__global__ __launch_bounds__(192) void k_iter3(const unsigned short* __restrict__ xw1b,
                                               const unsigned short* __restrict__ cw1,
                                               const unsigned short* __restrict__ pw1b,
                                               const unsigned short* __restrict__ projb,
                                               const float* __restrict__ b1,
                                               const float* __restrict__ w2,
                                               float* __restrict__ outc,
                                               float* __restrict__ outr) {
  __shared__ float red[3][NVIEW];
  __shared__ float aa[NVIEW];
  const int bn = blockIdx.x, t = threadIdx.x, wid = t >> 6, lane = t & 63;
  const int h = t * 4;
  const float4 bv = *(const float4*)(b1 + h);
  const float4 wv = *(const float4*)(w2 + h);
  float cw[4];
  { uint2 c = *(const uint2*)(cw1 + (size_t)bn * CDIM + h);
    cw[0] = bf_lo(c.x); cw[1] = bf_hi(c.x); cw[2] = bf_lo(c.y); cw[3] = bf_hi(c.y); }
  float xw[NVIEW][4], pf[NVIEW][4];
#pragma unroll
  for (int v = 0; v < NVIEW; ++v) {
    uint2 q = *(const uint2*)(xw1b + ((size_t)v * BN_TOT + bn) * CDIM + h);
    xw[v][0] = bf_lo(q.x) + bv.x; xw[v][1] = bf_hi(q.x) + bv.y;
    xw[v][2] = bf_lo(q.y) + bv.z; xw[v][3] = bf_hi(q.y) + bv.w;
    uint2 p = *(const uint2*)(pw1b + ((size_t)v * BN_TOT + bn) * CDIM + h);
    pf[v][0] = bf_lo(p.x); pf[v][1] = bf_hi(p.x);
    pf[v][2] = bf_lo(p.y); pf[v][3] = bf_hi(p.y);
  }
  for (int it = 0; it < 3; ++it) {
    float part[NVIEW];
#pragma unroll
    for (int v = 0; v < NVIEW; ++v) {
      float p;
      p = wv.x * ftanh(xw[v][0] + cw[0]);
      p = fmaf(wv.y, ftanh(xw[v][1] + cw[1]), p);
      p = fmaf(wv.z, ftanh(xw[v][2] + cw[2]), p);
      p = fmaf(wv.w, ftanh(xw[v][3] + cw[3]), p);
      part[v] = p;
    }
#pragma unroll
    for (int off = 32; off > 0; off >>= 1)
#pragma unroll
      for (int v = 0; v < NVIEW; ++v) part[v] += __shfl_down(part[v], off);
    if (lane == 0)
#pragma unroll
      for (int v = 0; v < NVIEW; ++v) red[wid][v] = part[v];
    __syncthreads();
    if (t == 0) {
      float s[NVIEW];
#pragma unroll
      for (int v = 0; v < NVIEW; ++v) s[v] = red[0][v] + red[1][v] + red[2][v];
      float m = s[0];
#pragma unroll
      for (int v = 1; v < NVIEW; ++v) m = fmaxf(m, s[v]);
      float a[NVIEW], sum = 0.f;
#pragma unroll
      for (int v = 0; v < NVIEW; ++v) { a[v] = __expf(s[v] - m); sum += a[v]; }
      const float inv = 1.f / sum;
#pragma unroll
      for (int v = 0; v < NVIEW; ++v) { a[v] *= inv; aa[v] = a[v]; }
      if (it == 2) {
        float ent = 0.f;
#pragma unroll
        for (int v = 0; v < NVIEW; ++v) ent -= a[v] * logf(a[v] + 1e-8f);
        outr[bn] = 1.f - ent * 0.6213349345596119f;  // 1/ln(5)
      }
    }
    __syncthreads();
    if (it < 2) {
      float n0 = 0, n1 = 0, n2 = 0, n3 = 0;
#pragma unroll
      for (int v = 0; v < NVIEW; ++v) {
        const float av = aa[v];
        n0 = fmaf(av, pf[v][0], n0); n1 = fmaf(av, pf[v][1], n1);
        n2 = fmaf(av, pf[v][2], n2); n3 = fmaf(av, pf[v][3], n3);
      }
      cw[0] = n0; cw[1] = n1; cw[2] = n2; cw[3] = n3;
    } else {
      float r0 = 0, r1 = 0, r2 = 0, r3 = 0;
#pragma unroll
      for (int v = 0; v < NVIEW; ++v) {
        const float av = aa[v];
        uint2 p = *(const uint2*)(projb + ((size_t)v * BN_TOT + bn) * CDIM + h);
        r0 = fmaf(av, bf_lo(p.x), r0); r1 = fmaf(av, bf_hi(p.x), r1);
        r2 = fmaf(av, bf_lo(p.y), r2); r3 = fmaf(av, bf_hi(p.y), r3);
      }
      float4 of; of.x = r0; of.y = r1; of.z = r2; of.w = r3;
      *(float4*)(outc + (size_t)bn * CDIM + h) = of;
    }
  }
}

extern "C" void kernel_launch(void* const* d_in, const int* in_sizes, int n_in,
                              void* d_out, int out_size, void* d_ws, size_t ws_size,
                              hipStream_t stream) {
  (void)in_sizes; (void)n_in; (void)out_size; (void)ws_size;
  const float* x  = (const float*)d_in[0];   // [B,V,N,C] fp32
  const float* wv = (const float*)d_in[1];   // [V,C,C]
  const float* w1 = (const float*)d_in[2];   // [2C,H]
  const float* b1 = (const float*)d_in[3];   // [H]
  const float* w2 = (const float*)d_in[4];   // [H,1]
  // d_in[5] = b2: uniform shift over views -> softmax-invariant, unused.

  // workspace: 86,016,000 ushorts = 172 MB (known-safe budget)
  unsigned short* ws   = (unsigned short*)d_ws;
  unsigned short* wvT  = ws;                   //  2,949,120
  unsigned short* w1aT = ws + 2949120;         //    589,824
  unsigned short* w1bT = ws + 3538944;         //    589,824
  unsigned short* projb= ws + 4128768;         // 24,084,480
  unsigned short* xw1b = ws + 28213248;        // 24,084,480
  unsigned short* wvB  = ws + 28213248;        //  2,949,120 (aliased: dead before xw1b written)
  unsigned short* pw1b = ws + 52297728;        // 24,084,480
  unsigned short* cb   = ws + 76382208;        //  4,816,896
  unsigned short* cw1  = ws + 81199104;        //  4,816,896 (end: 86,016,000)

  float* outc = (float*)d_out;                 // c [B,N,C] fp32
  float* outr = outc + SLAB;                   // r [B,N]   fp32
  // wpT lives in d_out: dead by the time k_iter3 overwrites outc (5.9 MB < 19.3 MB)
  unsigned short* wpT  = (unsigned short*)d_out;

  // 1: transposes + mean (mean needs only x; fills CUs while transposes run)
  k_tr2<<<dim3(24, 24, 8), dim3(32, 8), 0, stream>>>(wv, w1, x, wvT, w1aT, w1bT, wvB, cb);
  // 2: wpT_v = (wv_v @ w1b)^T  (180 works) + cw1 = cb @ w1b (294 works), one wall
  k_pre<<<474, 256, 0, stream>>>(w1bT, wvB, cb, wpT, cw1);
  // 3: main fused GEMM: proj_v | xw1_v | pw1b_v (4410 works, 4 blocks/CU target)
  gemm_m<<<4410, 256, 0, stream>>>(x, wvT, w1aT, wpT, projb, xw1b, pw1b);
  // 4: fused routing: 3 iterations pointwise in (b,n)
  k_iter3<<<BN_TOT, 192, 0, stream>>>(xw1b, cw1, pw1b, projb, b1, w2, outc, outr);
}

// Round 5
// 413.014 us; speedup vs baseline: 1.0565x; 1.0565x over previous
//
#include <hip/hip_runtime.h>

// ---------- problem constants ----------
#define CDIM   768
#define NSEQ   196
#define NVIEW  5
#define BN_TOT 6272       // B*N
#define SLAB   4816896    // BN_TOT*CDIM
#define WSLAB  589824     // CDIM*CDIM

typedef __attribute__((ext_vector_type(8))) short short8;  // 8 bf16 (4 VGPRs)
typedef __attribute__((ext_vector_type(4))) float f32x4;

// ---------- helpers ----------
__device__ __forceinline__ float bf_lo(unsigned u) { return __uint_as_float(u << 16); }
__device__ __forceinline__ float bf_hi(unsigned u) { return __uint_as_float(u & 0xffff0000u); }
__device__ __forceinline__ unsigned short f2bf(float f) {
  unsigned u = __float_as_uint(f);
  return (unsigned short)((u + 0x7fffu + ((u >> 16) & 1u)) >> 16);  // RNE
}
__device__ __forceinline__ unsigned pack2(float f0, float f1) {
  return (unsigned)f2bf(f0) | ((unsigned)f2bf(f1) << 16);
}
__device__ __forceinline__ float ftanh(float x) {
  x = fminf(fmaxf(x, -10.f), 10.f);
  float e = __expf(2.f * x);
  return (e - 1.f) / (e + 1.f);
}
__device__ __forceinline__ void async_cp16(const void* g, void* l) {
  __builtin_amdgcn_global_load_lds((const __attribute__((address_space(1))) unsigned*)g,
                                   (__attribute__((address_space(3))) unsigned*)l, 16, 0, 0);
}

// ---------- launch 1: weight transposes (z<7) + mean over views (z==7) ----------
// (verified in R4) z<7: fp32->bf16 transposes of 7 768x768 mats (+ bf16 wv copy).
// z==7: cb[bn][c] = bf16(mean_v x) — 576 blocks x 11 bn, threads 0..191 do 4 cols.
__global__ __launch_bounds__(256) void k_tr2(const float* __restrict__ wv,
                                             const float* __restrict__ w1,
                                             const float* __restrict__ x,
                                             unsigned short* __restrict__ wvT,
                                             unsigned short* __restrict__ w1aT,
                                             unsigned short* __restrict__ w1bT,
                                             unsigned short* __restrict__ wvB,
                                             unsigned short* __restrict__ cb) {
  const int m = blockIdx.z;
  const int tx = threadIdx.x, ty = threadIdx.y, t = ty * 32 + tx;
  if (m == 7) {               // ---- mean works ----
    const int bidx = blockIdx.y * 24 + blockIdx.x;   // 0..575
    if (t < 192) {
      const int col = t * 4;
      for (int i = 0; i < 11; ++i) {
        const int bn = bidx * 11 + i;
        if (bn >= BN_TOT) break;
        const int b = bn / NSEQ, n = bn - b * NSEQ;
        const float* xp = x + ((size_t)(b * NVIEW) * NSEQ + n) * CDIM + col;
        float s0 = 0, s1 = 0, s2 = 0, s3 = 0;
#pragma unroll
        for (int v = 0; v < NVIEW; ++v) {
          float4 p = *(const float4*)(xp + (size_t)v * (NSEQ * CDIM));
          s0 += p.x; s1 += p.y; s2 += p.z; s3 += p.w;
        }
        uint2 o;
        o.x = pack2(s0 * 0.2f, s1 * 0.2f);
        o.y = pack2(s2 * 0.2f, s3 * 0.2f);
        *(uint2*)(cb + (size_t)bn * CDIM + col) = o;
      }
    }
    return;
  }
  __shared__ float tile[32][33];
  const float* src;
  unsigned short* dst;
  unsigned short* dstB = nullptr;
  if (m < NVIEW)      { src = wv + (size_t)m * WSLAB; dst = wvT + (size_t)m * WSLAB;
                        dstB = wvB + (size_t)m * WSLAB; }
  else if (m == NVIEW){ src = w1;                     dst = w1aT; }
  else                { src = w1 + WSLAB;             dst = w1bT; }
  const int x0 = blockIdx.x * 32, y0 = blockIdx.y * 32;
#pragma unroll
  for (int i = 0; i < 4; ++i) {
    float v = src[(size_t)(y0 + ty + i * 8) * CDIM + x0 + tx];
    tile[ty + i * 8][tx] = v;
    if (dstB) dstB[(size_t)(y0 + ty + i * 8) * CDIM + x0 + tx] = f2bf(v);
  }
  __syncthreads();
#pragma unroll
  for (int i = 0; i < 4; ++i)
    dst[(size_t)(x0 + ty + i * 8) * CDIM + y0 + tx] = f2bf(tile[tx][ty + i * 8]);
}

// ---------- launch 2: wpT_v = w1bT @ wvB_v^T (180 works of 128x128) ----------
// (R4's k_pre body, verified; wpT-only so the solo wall is ~10 us not 36)
__global__ __launch_bounds__(256, 4) void k_pre(const unsigned short* __restrict__ w1bT,
                                                const unsigned short* __restrict__ wvB,
                                                unsigned short* __restrict__ wpT) {
  __shared__ __align__(16) unsigned short lds[16384];   // 2 slots x (A 4096 + B 4096)
  const int wk = blockIdx.x;
  const int t = threadIdx.x, w = t >> 6, lane = t & 63, lr = lane & 15, lq = lane >> 4;
  const int wm = (w >> 1) * 64, wn = (w & 1) * 64;
  const int v = wk / 36, rem = wk % 36;
  const int mrow0 = (rem / 6) * 128, colBase = (rem % 6) * 128;
  const unsigned short* Abf = w1bT;
  const unsigned short* Bt = wvB + (size_t)v * WSLAB;
  unsigned short* C = wpT + (size_t)v * WSLAB;
  const int swz = ((t & 3) ^ ((t >> 3) & 3)) << 3;
  const unsigned short* gA = Abf + (size_t)(mrow0 + (t >> 2)) * CDIM + swz;
  const unsigned short* gB = Bt + (size_t)(colBase + (t >> 2)) * CDIM + swz;
  const int kch = ((lq ^ ((lr >> 1) & 3)) << 3);
#define CPA(kt, s) { unsigned short* d_ = lds + (s) * 8192 + (w << 9);                  \
    async_cp16(gA + (kt) * 32, d_);                                                     \
    async_cp16(gA + (kt) * 32 + (size_t)64 * CDIM, d_ + 2048); }
#define CPB(kt, s) { unsigned short* d_ = lds + (s) * 8192 + 4096 + (w << 9);           \
    async_cp16(gB + (kt) * 32, d_);                                                     \
    async_cp16(gB + (kt) * 32 + (size_t)64 * CDIM, d_ + 2048); }
  f32x4 acc[4][4] = {};
  CPA(0, 0); CPB(0, 0);
  asm volatile("s_waitcnt vmcnt(0)" ::: "memory");
  __builtin_amdgcn_s_barrier();
  for (int kt = 0; kt < 24; ++kt) {
    const int s = kt & 1;
    const unsigned short* bp = lds + s * 8192;
    if (kt < 23) { CPA(kt + 1, s ^ 1); CPB(kt + 1, s ^ 1); }
    short8 af[4], bf[4];
#pragma unroll
    for (int i = 0; i < 4; ++i) af[i] = *(const short8*)(bp + (wm + i * 16 + lr) * 32 + kch);
#pragma unroll
    for (int j = 0; j < 4; ++j) bf[j] = *(const short8*)(bp + 4096 + (wn + j * 16 + lr) * 32 + kch);
    __builtin_amdgcn_s_setprio(1);
#pragma unroll
    for (int i = 0; i < 4; ++i)
#pragma unroll
      for (int j = 0; j < 4; ++j)
        acc[i][j] = __builtin_amdgcn_mfma_f32_16x16x32_bf16(af[i], bf[j], acc[i][j], 0, 0, 0);
    __builtin_amdgcn_s_setprio(0);
    asm volatile("s_waitcnt vmcnt(0) lgkmcnt(0)" ::: "memory");
    __builtin_amdgcn_s_barrier();
  }
#undef CPA
#undef CPB
#pragma unroll
  for (int i = 0; i < 4; ++i)
#pragma unroll
    for (int j = 0; j < 4; ++j) {
      const int gr = mrow0 + wm + i * 16 + lq * 4;
      const int gc = colBase + wn + j * 16 + lr;
      unsigned short* cp = C + (size_t)gr * CDIM + gc;
#pragma unroll
      for (int r = 0; r < 4; ++r)
        cp[(size_t)r * CDIM] = f2bf(acc[i][j][r]);
    }
}

// ---------- launch 3: main GEMM — R3's 512-thr 128x256 body, 16 z-slabs ----------
// works 2352 = 16z x 49mt x 3nt, decode nt-fastest (B-panel L2 reuse per R0).
// z<15: v=z%5, sub=z/5: Bt in {wvT_v, w1aT, wpT_v}, C in {projb, xw1b, pw1b}_v;
//   A = x[:,v] fp32, reg-staged + packed (R3 MODE-0 path, verified, 722 TF).
// z==15: A = cb bf16 via global_load_lds (R3 MODE-2 path, verified), C = cw1.
// 2-ring 48 KiB LDS, full drain per K-tile; block-TLP hides the drains.
// XOR swizzle on pre-swizzled global source / write-side + matching ds_read.
__global__ __launch_bounds__(512, 4) void gemm_m16(const float* __restrict__ X,
                                                   const unsigned short* __restrict__ wvT,
                                                   const unsigned short* __restrict__ w1aT,
                                                   const unsigned short* __restrict__ wpT,
                                                   const unsigned short* __restrict__ w1bT,
                                                   const unsigned short* __restrict__ cb,
                                                   unsigned short* __restrict__ projb,
                                                   unsigned short* __restrict__ xw1b,
                                                   unsigned short* __restrict__ pw1b,
                                                   unsigned short* __restrict__ cw1) {
  __shared__ __align__(16) unsigned short lds[2 * 12288];  // 2 slots x (A 4096 + B 8192) shorts
  // XCD swizzle: 2352 = 8 * 294 exactly
  const int orig = blockIdx.x;
  const int wk = (orig & 7) * 294 + (orig >> 3);
  const int nt = wk % 3, mt = (wk / 3) % 49, z = wk / 147;
  const int t = threadIdx.x, w = t >> 6, lane = t & 63, lr = lane & 15, lq = lane >> 4;
  const int wm = ((w >> 2) & 1) * 64;   // 0 / 64
  const int wn = (w & 3) * 64;          // 0 / 64 / 128 / 192
  const int colBase = nt * 256, mrow0 = mt * 128;

  const bool zc = (z < 15);             // block-uniform branch
  const unsigned short* Bt;
  unsigned short* C;
  const float* aPtr = nullptr;
  if (zc) {
    const int v = z % 5, sub = z / 5;
    Bt = (sub == 0) ? wvT + (size_t)v * WSLAB : (sub == 1) ? w1aT : wpT + (size_t)v * WSLAB;
    C  = ((sub == 0) ? projb : (sub == 1) ? xw1b : pw1b) + (size_t)v * SLAB;
    const int r = mrow0 + (t >> 2);
    const int b = r / NSEQ, n = r - b * NSEQ;
    aPtr = X + (size_t)((b * NVIEW + v) * NSEQ + n) * CDIM + (t & 3) * 8;
  } else {
    Bt = w1bT; C = cw1;
  }

  const int swz = ((t & 3) ^ ((t >> 3) & 3)) << 3;
  const unsigned short* gB = Bt + (size_t)(colBase + (t >> 2)) * CDIM + swz;
  const unsigned short* gAb = zc ? nullptr
                                 : cb + (size_t)(mrow0 + (t >> 2)) * CDIM + swz;
  const int aswz = swz;                 // fp32-A: write-side swizzle (same involution)
  const int kch = ((lq ^ ((lr >> 1) & 3)) << 3);

#define STB(kt, s) { const unsigned short* sp_ = gB + (kt) * 32;                  \
    unsigned short* dp_ = lds + (s) * 12288 + 4096 + (w << 9);                    \
    async_cp16(sp_, dp_); async_cp16(sp_ + (size_t)128 * CDIM, dp_ + 4096); }
#define STA1(kt, s) { async_cp16(gAb + (kt) * 32, lds + (s) * 12288 + (w << 9)); }
#define STA0W(s) { uint4 qv_;                                                     \
    qv_.x = pack2(pa0.x, pa0.y); qv_.y = pack2(pa0.z, pa0.w);                     \
    qv_.z = pack2(pa1.x, pa1.y); qv_.w = pack2(pa1.z, pa1.w);                     \
    *(uint4*)(lds + (s) * 12288 + (t >> 2) * 32 + aswz) = qv_; }

  f32x4 acc[4][4] = {};
  float4 pa0{}, pa1{};

  // ---- prologue: stage K-tile 0 into slot 0 ----
  if (zc) { pa0 = *(const float4*)(aPtr); pa1 = *(const float4*)(aPtr + 4); }
  else    { STA1(0, 0); }
  STB(0, 0);
  if (zc) STA0W(0);
  asm volatile("s_waitcnt vmcnt(0) lgkmcnt(0)" ::: "memory");
  __builtin_amdgcn_s_barrier();

  for (int kt = 0; kt < 24; ++kt) {
    const int s = kt & 1;
    const unsigned short* bp = lds + s * 12288;
    const bool pf = (kt < 23);
    if (pf) {   // issue next tile early: fp32 A loads + B DMA into the free slot
      if (zc) {
        pa0 = *(const float4*)(aPtr + (kt + 1) * 32);
        pa1 = *(const float4*)(aPtr + (kt + 1) * 32 + 4);
      } else { STA1(kt + 1, s ^ 1); }
      STB(kt + 1, s ^ 1);
    }
    short8 af[4], bf[4];
#pragma unroll
    for (int i = 0; i < 4; ++i) af[i] = *(const short8*)(bp + (wm + i * 16 + lr) * 32 + kch);
#pragma unroll
    for (int j = 0; j < 4; ++j) bf[j] = *(const short8*)(bp + 4096 + (wn + j * 16 + lr) * 32 + kch);
    __builtin_amdgcn_s_setprio(1);
#pragma unroll
    for (int i = 0; i < 4; ++i)
#pragma unroll
      for (int j = 0; j < 4; ++j)
        acc[i][j] = __builtin_amdgcn_mfma_f32_16x16x32_bf16(af[i], bf[j], acc[i][j], 0, 0, 0);
    __builtin_amdgcn_s_setprio(0);
    if (pf && zc) STA0W(s ^ 1);          // a-loads had the MFMA window to land
    asm volatile("s_waitcnt vmcnt(0) lgkmcnt(0)" ::: "memory");
    __builtin_amdgcn_s_barrier();
  }
#undef STB
#undef STA1
#undef STA0W

  // ---- epilogue (M % 128 == 0 for all slabs) ----
#pragma unroll
  for (int i = 0; i < 4; ++i)
#pragma unroll
    for (int j = 0; j < 4; ++j) {
      const int gr = mrow0 + wm + i * 16 + lq * 4;   // C/D: row=(lane>>4)*4+reg, col=lane&15
      const int gc = colBase + wn + j * 16 + lr;
      unsigned short* cp = C + (size_t)gr * CDIM + gc;
#pragma unroll
      for (int r = 0; r < 4; ++r)
        cp[(size_t)r * CDIM] = f2bf(acc[i][j][r]);
    }
}

// ---------- fully fused routing loop: 3x (scores -> softmax -> weighted sum), pointwise in bn ----------
__global__ __launch_bounds__(192) void k_iter3(const unsigned short* __restrict__ xw1b,
                                               const unsigned short* __restrict__ cw1,
                                               const unsigned short* __restrict__ pw1b,
                                               const unsigned short* __restrict__ projb,
                                               const float* __restrict__ b1,
                                               const float* __restrict__ w2,
                                               float* __restrict__ outc,
                                               float* __restrict__ outr) {
  __shared__ float red[3][NVIEW];
  __shared__ float aa[NVIEW];
  const int bn = blockIdx.x, t = threadIdx.x, wid = t >> 6, lane = t & 63;
  const int h = t * 4;
  const float4 bv = *(const float4*)(b1 + h);
  const float4 wv = *(const float4*)(w2 + h);
  float cw[4];
  { uint2 c = *(const uint2*)(cw1 + (size_t)bn * CDIM + h);
    cw[0] = bf_lo(c.x); cw[1] = bf_hi(c.x); cw[2] = bf_lo(c.y); cw[3] = bf_hi(c.y); }
  float xw[NVIEW][4], pf[NVIEW][4];
#pragma unroll
  for (int v = 0; v < NVIEW; ++v) {
    uint2 q = *(const uint2*)(xw1b + ((size_t)v * BN_TOT + bn) * CDIM + h);
    xw[v][0] = bf_lo(q.x) + bv.x; xw[v][1] = bf_hi(q.x) + bv.y;
    xw[v][2] = bf_lo(q.y) + bv.z; xw[v][3] = bf_hi(q.y) + bv.w;
    uint2 p = *(const uint2*)(pw1b + ((size_t)v * BN_TOT + bn) * CDIM + h);
    pf[v][0] = bf_lo(p.x); pf[v][1] = bf_hi(p.x);
    pf[v][2] = bf_lo(p.y); pf[v][3] = bf_hi(p.y);
  }
  for (int it = 0; it < 3; ++it) {
    float part[NVIEW];
#pragma unroll
    for (int v = 0; v < NVIEW; ++v) {
      float p;
      p = wv.x * ftanh(xw[v][0] + cw[0]);
      p = fmaf(wv.y, ftanh(xw[v][1] + cw[1]), p);
      p = fmaf(wv.z, ftanh(xw[v][2] + cw[2]), p);
      p = fmaf(wv.w, ftanh(xw[v][3] + cw[3]), p);
      part[v] = p;
    }
#pragma unroll
    for (int off = 32; off > 0; off >>= 1)
#pragma unroll
      for (int v = 0; v < NVIEW; ++v) part[v] += __shfl_down(part[v], off);
    if (lane == 0)
#pragma unroll
      for (int v = 0; v < NVIEW; ++v) red[wid][v] = part[v];
    __syncthreads();
    if (t == 0) {
      float s[NVIEW];
#pragma unroll
      for (int v = 0; v < NVIEW; ++v) s[v] = red[0][v] + red[1][v] + red[2][v];
      float m = s[0];
#pragma unroll
      for (int v = 1; v < NVIEW; ++v) m = fmaxf(m, s[v]);
      float a[NVIEW], sum = 0.f;
#pragma unroll
      for (int v = 0; v < NVIEW; ++v) { a[v] = __expf(s[v] - m); sum += a[v]; }
      const float inv = 1.f / sum;
#pragma unroll
      for (int v = 0; v < NVIEW; ++v) { a[v] *= inv; aa[v] = a[v]; }
      if (it == 2) {
        float ent = 0.f;
#pragma unroll
        for (int v = 0; v < NVIEW; ++v) ent -= a[v] * logf(a[v] + 1e-8f);
        outr[bn] = 1.f - ent * 0.6213349345596119f;  // 1/ln(5)
      }
    }
    __syncthreads();
    if (it < 2) {
      float n0 = 0, n1 = 0, n2 = 0, n3 = 0;
#pragma unroll
      for (int v = 0; v < NVIEW; ++v) {
        const float av = aa[v];
        n0 = fmaf(av, pf[v][0], n0); n1 = fmaf(av, pf[v][1], n1);
        n2 = fmaf(av, pf[v][2], n2); n3 = fmaf(av, pf[v][3], n3);
      }
      cw[0] = n0; cw[1] = n1; cw[2] = n2; cw[3] = n3;
    } else {
      float r0 = 0, r1 = 0, r2 = 0, r3 = 0;
#pragma unroll
      for (int v = 0; v < NVIEW; ++v) {
        const float av = aa[v];
        uint2 p = *(const uint2*)(projb + ((size_t)v * BN_TOT + bn) * CDIM + h);
        r0 = fmaf(av, bf_lo(p.x), r0); r1 = fmaf(av, bf_hi(p.x), r1);
        r2 = fmaf(av, bf_lo(p.y), r2); r3 = fmaf(av, bf_hi(p.y), r3);
      }
      float4 of; of.x = r0; of.y = r1; of.z = r2; of.w = r3;
      *(float4*)(outc + (size_t)bn * CDIM + h) = of;
    }
  }
}

extern "C" void kernel_launch(void* const* d_in, const int* in_sizes, int n_in,
                              void* d_out, int out_size, void* d_ws, size_t ws_size,
                              hipStream_t stream) {
  (void)in_sizes; (void)n_in; (void)out_size; (void)ws_size;
  const float* x  = (const float*)d_in[0];   // [B,V,N,C] fp32
  const float* wv = (const float*)d_in[1];   // [V,C,C]
  const float* w1 = (const float*)d_in[2];   // [2C,H]
  const float* b1 = (const float*)d_in[3];   // [H]
  const float* w2 = (const float*)d_in[4];   // [H,1]
  // d_in[5] = b2: uniform shift over views -> softmax-invariant, unused.

  // workspace: 86,016,000 ushorts = 172 MB (exactly the known-safe size)
  unsigned short* ws   = (unsigned short*)d_ws;
  unsigned short* wvT  = ws;                   //  2,949,120
  unsigned short* w1aT = ws + 2949120;         //    589,824
  unsigned short* w1bT = ws + 3538944;         //    589,824
  unsigned short* projb= ws + 4128768;         // 24,084,480
  unsigned short* xw1b = ws + 28213248;        // 24,084,480
  unsigned short* wvB  = ws + 28213248;        //  2,949,120 (alias: dead before xw1b written)
  unsigned short* pw1b = ws + 52297728;        // 24,084,480
  unsigned short* cb   = ws + 76382208;        //  4,816,896
  unsigned short* cw1  = ws + 81199104;        //  4,816,896 (end: 86,016,000)

  float* outc = (float*)d_out;                 // c [B,N,C] fp32
  float* outr = outc + SLAB;                   // r [B,N]   fp32
  // wpT lives in d_out (5.9 MB < 19.3 MB): only read by gemm_m16, which
  // completes before k_iter3 writes outc. (cw1 alias from R3 would race now.)
  unsigned short* wpT  = (unsigned short*)d_out;

  // 1: transposes + mean (one launch; mean plane fills CUs beside transposes)
  k_tr2<<<dim3(24, 24, 8), dim3(32, 8), 0, stream>>>(wv, w1, x, wvT, w1aT, w1bT, wvB, cb);
  // 2: wpT_v = (wv_v @ w1b)^T — 180 small blocks, ~10 us wall
  k_pre<<<180, 256, 0, stream>>>(w1bT, wvB, wpT);
  // 3: main GEMM: proj | xw1 | pw1b | cw1, one grid (2352 works, 512 thr)
  gemm_m16<<<2352, 512, 0, stream>>>(x, wvT, w1aT, wpT, w1bT, cb,
                                     projb, xw1b, pw1b, cw1);
  // 4: fused routing: 3 iterations pointwise in (b,n)
  k_iter3<<<BN_TOT, 192, 0, stream>>>(xw1b, cw1, pw1b, projb, b1, w2, outc, outr);
}

// Round 7
// 357.183 us; speedup vs baseline: 1.2216x; 1.1563x over previous
//
#include <hip/hip_runtime.h>

// ---------- problem constants ----------
#define CDIM   768
#define NSEQ   196
#define NVIEW  5
#define BN_TOT 6272       // B*N
#define SLAB   4816896    // BN_TOT*CDIM
#define WSLAB  589824     // CDIM*CDIM

typedef __attribute__((ext_vector_type(8))) short short8;  // 8 bf16 (4 VGPRs)
typedef __attribute__((ext_vector_type(4))) float f32x4;

// ---------- helpers ----------
__device__ __forceinline__ float bf_lo(unsigned u) { return __uint_as_float(u << 16); }
__device__ __forceinline__ float bf_hi(unsigned u) { return __uint_as_float(u & 0xffff0000u); }
__device__ __forceinline__ unsigned short f2bf(float f) {
  unsigned u = __float_as_uint(f);
  return (unsigned short)((u + 0x7fffu + ((u >> 16) & 1u)) >> 16);  // RNE
}
__device__ __forceinline__ unsigned pack2(float f0, float f1) {
  return (unsigned)f2bf(f0) | ((unsigned)f2bf(f1) << 16);
}
__device__ __forceinline__ float ftanh(float x) {
  x = fminf(fmaxf(x, -10.f), 10.f);
  float e = __expf(2.f * x);
  return (e - 1.f) / (e + 1.f);
}
__device__ __forceinline__ void async_cp16(const void* g, void* l) {
  __builtin_amdgcn_global_load_lds((const __attribute__((address_space(1))) unsigned*)g,
                                   (__attribute__((address_space(3))) unsigned*)l, 16, 0, 0);
}

// ---------- weight transpose fp32 -> bf16: 7 matrices of 768x768 (R0 exact) ----------
__global__ __launch_bounds__(256) void k_tr(const float* __restrict__ wv,
                                            const float* __restrict__ w1,
                                            unsigned short* __restrict__ wvT,
                                            unsigned short* __restrict__ w1aT,
                                            unsigned short* __restrict__ w1bT) {
  __shared__ float tile[32][33];
  const int m = blockIdx.z;
  const float* src;
  unsigned short* dst;
  if (m < NVIEW)      { src = wv + (size_t)m * WSLAB; dst = wvT + (size_t)m * WSLAB; }
  else if (m == NVIEW){ src = w1;                     dst = w1aT; }
  else                { src = w1 + WSLAB;             dst = w1bT; }
  const int tx = threadIdx.x, ty = threadIdx.y;
  const int x0 = blockIdx.x * 32, y0 = blockIdx.y * 32;
#pragma unroll
  for (int i = 0; i < 4; ++i)
    tile[ty + i * 8][tx] = src[(size_t)(y0 + ty + i * 8) * CDIM + x0 + tx];
  __syncthreads();
#pragma unroll
  for (int i = 0; i < 4; ++i)
    dst[(size_t)(x0 + ty + i * 8) * CDIM + y0 + tx] = f2bf(tile[tx][ty + i * 8]);
}

// ---------- single pass over x: xb[v][bn][c] = bf16(x), cb = mean over v (R0 exact) ----------
__global__ __launch_bounds__(192) void k_cvt_mean(const float* __restrict__ x,
                                                  unsigned short* __restrict__ xb,
                                                  unsigned short* __restrict__ cb) {
  const int bn = blockIdx.x;
  const int b = bn / NSEQ, n = bn % NSEQ;
  const int h = threadIdx.x * 4;
  const float* xp = x + ((size_t)(b * NVIEW) * NSEQ + n) * CDIM + h;
  float s0 = 0, s1 = 0, s2 = 0, s3 = 0;
#pragma unroll
  for (int v = 0; v < NVIEW; ++v) {
    float4 p = *(const float4*)(xp + (size_t)v * (NSEQ * CDIM));
    s0 += p.x; s1 += p.y; s2 += p.z; s3 += p.w;
    uint2 q; q.x = pack2(p.x, p.y); q.y = pack2(p.z, p.w);
    *(uint2*)(xb + ((size_t)v * BN_TOT + bn) * CDIM + h) = q;
  }
  uint2 o;
  o.x = pack2(s0 * 0.2f, s1 * 0.2f);
  o.y = pack2(s2 * 0.2f, s3 * 0.2f);
  *(uint2*)(cb + (size_t)bn * CDIM + h) = o;
}

// ---------- 128x256-tile GEMM, 3-deep LDS ring, counted vmcnt, 2 blocks/CU ----------
// (identical resubmission of R6 source: container-level infra failure, same
//  signature as R2 which reran clean in R3; full hang-audit in journal — no
//  deadlock path: vmcnt waits with fewer outstanding return immediately,
//  slot (kt+2)%3 was consumed before the kt-1 barrier, no divergent barriers.)
// R0's DAG + buffers; ONLY delta vs champion: ring schedule. All staging is
// global_load_lds DMA (3 ops/tile: A 8KB x1, B 16KB x2). Per K-tile:
//   stage kt+2 -> slot (kt+2)%3 ; ds_read kt ; 16 MFMA ; vmcnt(3) ; barrier
// vmcnt(3) = kt+2's 3 ops stay in flight, kt+1's 3 proven landed -> the
// pipeline never drains until the tail (kt=22: vmcnt(0)).
// 3 slots x 24KB = 72KB dynamic LDS; __launch_bounds__(512,4) caps regs ->
// 2 blocks/CU (144KB LDS), sibling block hides residual latency (m114).
// XOR swizzle (chunk ^= (row>>1)&3): pre-swizzled global source + ds_read.
// MODE 0 (1617 works = 11z x 49mt x 3nt): z<5 proj=xb_v@wvT_v ; z in[5,10)
//   xw1=xb_v@w1aT ; z==10 cw1=cb@w1bT.
// MODE 1 (735 works = 5z x 49mt x 3nt): pw1b_v = projb_v @ w1bT.
template <int MODE>
__global__ __launch_bounds__(512, 4) void gemm_r(const unsigned short* __restrict__ P0,
                                                 const unsigned short* __restrict__ cbp,
                                                 const unsigned short* __restrict__ wvT,
                                                 const unsigned short* __restrict__ w1aT,
                                                 const unsigned short* __restrict__ w1bT,
                                                 unsigned short* __restrict__ Q0,
                                                 unsigned short* __restrict__ Q1,
                                                 unsigned short* __restrict__ Q2) {
  extern __shared__ unsigned short ldsb[];   // 3 slots x (A 4096 + B 8192) shorts = 72 KB
  constexpr int NWG = (MODE == 0) ? 1617 : 735;
  // bijective XCD swizzle (m204)
  const int orig = blockIdx.x;
  const int qq = NWG >> 3, rr = NWG & 7, xcd = orig & 7, slot0 = orig >> 3;
  const int wk = (xcd < rr ? xcd * (qq + 1) : rr * (qq + 1) + (xcd - rr) * qq) + slot0;
  const int nt = wk % 3, mt = (wk / 3) % 49, z = wk / 147;

  const int t = threadIdx.x, w = t >> 6, lane = t & 63, lr = lane & 15, lq = lane >> 4;
  const int wm = ((w >> 2) & 1) * 64;   // 0 / 64
  const int wn = (w & 3) * 64;          // 0 / 64 / 128 / 192
  const int colBase = nt * 256, mrow0 = mt * 128;

  const unsigned short *A, *Bt;
  unsigned short* C;
  if (MODE == 0) {
    if (z == 10)    { A = cbp; Bt = w1bT; C = Q2; }
    else if (z < 5) { A = P0 + (size_t)z * SLAB;       Bt = wvT + (size_t)z * WSLAB; C = Q0 + (size_t)z * SLAB; }
    else            { A = P0 + (size_t)(z - 5) * SLAB; Bt = w1aT;                    C = Q1 + (size_t)(z - 5) * SLAB; }
  } else {
    A = P0 + (size_t)z * SLAB; Bt = w1bT; C = Q0 + (size_t)z * SLAB;
  }

  // staging sources (pre-swizzled k-chunk; DMA dest is linear: rule-21 pair)
  const int swz = ((t & 3) ^ ((t >> 3) & 3)) << 3;
  const unsigned short* gA = A  + (size_t)(mrow0 + (t >> 2)) * CDIM + swz;
  const unsigned short* gB = Bt + (size_t)(colBase + (t >> 2)) * CDIM + swz;
  // ds_read address (same involution: chunk = lq ^ ((lr>>1)&3))
  const int kch = ((lq ^ ((lr >> 1) & 3)) << 3);

  // 3 vmcnt-ops per tile: A(1) + B(2). Wave w's DMA dest = uniform base + lane*16B.
#define STAGE(kt, s) {                                                            \
    unsigned short* d_ = ldsb + (s) * 12288 + (w << 9);                           \
    async_cp16(gA + (kt) * 32, d_);                                               \
    async_cp16(gB + (kt) * 32, d_ + 4096);                                        \
    async_cp16(gB + (kt) * 32 + (size_t)128 * CDIM, d_ + 8192); }

  f32x4 acc[4][4] = {};

  // prologue: stage tiles 0,1 ; ensure tile 0 landed (tile 1's 3 stay in flight)
  STAGE(0, 0); STAGE(1, 1);
  asm volatile("s_waitcnt vmcnt(3)" ::: "memory");
  __builtin_amdgcn_s_barrier();

  for (int kt = 0; kt < 24; ++kt) {
    const int s = kt % 3;
    const unsigned short* bp = ldsb + s * 12288;
    if (kt < 22) STAGE(kt + 2, (kt + 2) % 3);
    short8 af[4], bf[4];
#pragma unroll
    for (int i = 0; i < 4; ++i) af[i] = *(const short8*)(bp + (wm + i * 16 + lr) * 32 + kch);
#pragma unroll
    for (int j = 0; j < 4; ++j) bf[j] = *(const short8*)(bp + 4096 + (wn + j * 16 + lr) * 32 + kch);
    __builtin_amdgcn_s_setprio(1);
#pragma unroll
    for (int i = 0; i < 4; ++i)
#pragma unroll
      for (int j = 0; j < 4; ++j)
        acc[i][j] = __builtin_amdgcn_mfma_f32_16x16x32_bf16(af[i], bf[j], acc[i][j], 0, 0, 0);
    __builtin_amdgcn_s_setprio(0);
    if (kt < 22)       { asm volatile("s_waitcnt vmcnt(3)" ::: "memory"); }  // kt+1 landed
    else if (kt == 22) { asm volatile("s_waitcnt vmcnt(0)" ::: "memory"); }  // tail drain
    __builtin_amdgcn_s_barrier();
  }
#undef STAGE

  // epilogue (M % 128 == 0 everywhere)
#pragma unroll
  for (int i = 0; i < 4; ++i)
#pragma unroll
    for (int j = 0; j < 4; ++j) {
      const int gr = mrow0 + wm + i * 16 + lq * 4;   // C/D: row=(lane>>4)*4+reg, col=lane&15
      const int gc = colBase + wn + j * 16 + lr;
      unsigned short* cp = C + (size_t)gr * CDIM + gc;
#pragma unroll
      for (int r = 0; r < 4; ++r)
        cp[(size_t)r * CDIM] = f2bf(acc[i][j][r]);
    }
}

// ---------- fully fused routing loop (R0 exact) ----------
__global__ __launch_bounds__(192) void k_iter3(const unsigned short* __restrict__ xw1b,
                                               const unsigned short* __restrict__ cw1,
                                               const unsigned short* __restrict__ pw1b,
                                               const unsigned short* __restrict__ projb,
                                               const float* __restrict__ b1,
                                               const float* __restrict__ w2,
                                               float* __restrict__ outc,
                                               float* __restrict__ outr) {
  __shared__ float red[3][NVIEW];
  __shared__ float aa[NVIEW];
  const int bn = blockIdx.x, t = threadIdx.x, wid = t >> 6, lane = t & 63;
  const int h = t * 4;
  const float4 bv = *(const float4*)(b1 + h);
  const float4 wv = *(const float4*)(w2 + h);
  float cw[4];
  { uint2 c = *(const uint2*)(cw1 + (size_t)bn * CDIM + h);
    cw[0] = bf_lo(c.x); cw[1] = bf_hi(c.x); cw[2] = bf_lo(c.y); cw[3] = bf_hi(c.y); }
  float xw[NVIEW][4], pf[NVIEW][4];
#pragma unroll
  for (int v = 0; v < NVIEW; ++v) {
    uint2 q = *(const uint2*)(xw1b + ((size_t)v * BN_TOT + bn) * CDIM + h);
    xw[v][0] = bf_lo(q.x) + bv.x; xw[v][1] = bf_hi(q.x) + bv.y;
    xw[v][2] = bf_lo(q.y) + bv.z; xw[v][3] = bf_hi(q.y) + bv.w;
    uint2 p = *(const uint2*)(pw1b + ((size_t)v * BN_TOT + bn) * CDIM + h);
    pf[v][0] = bf_lo(p.x); pf[v][1] = bf_hi(p.x);
    pf[v][2] = bf_lo(p.y); pf[v][3] = bf_hi(p.y);
  }
  for (int it = 0; it < 3; ++it) {
    float part[NVIEW];
#pragma unroll
    for (int v = 0; v < NVIEW; ++v) {
      float p;
      p = wv.x * ftanh(xw[v][0] + cw[0]);
      p = fmaf(wv.y, ftanh(xw[v][1] + cw[1]), p);
      p = fmaf(wv.z, ftanh(xw[v][2] + cw[2]), p);
      p = fmaf(wv.w, ftanh(xw[v][3] + cw[3]), p);
      part[v] = p;
    }
#pragma unroll
    for (int off = 32; off > 0; off >>= 1)
#pragma unroll
      for (int v = 0; v < NVIEW; ++v) part[v] += __shfl_down(part[v], off);
    if (lane == 0)
#pragma unroll
      for (int v = 0; v < NVIEW; ++v) red[wid][v] = part[v];
    __syncthreads();
    if (t == 0) {
      float s[NVIEW];
#pragma unroll
      for (int v = 0; v < NVIEW; ++v) s[v] = red[0][v] + red[1][v] + red[2][v];
      float m = s[0];
#pragma unroll
      for (int v = 1; v < NVIEW; ++v) m = fmaxf(m, s[v]);
      float a[NVIEW], sum = 0.f;
#pragma unroll
      for (int v = 0; v < NVIEW; ++v) { a[v] = __expf(s[v] - m); sum += a[v]; }
      const float inv = 1.f / sum;
#pragma unroll
      for (int v = 0; v < NVIEW; ++v) { a[v] *= inv; aa[v] = a[v]; }
      if (it == 2) {
        float ent = 0.f;
#pragma unroll
        for (int v = 0; v < NVIEW; ++v) ent -= a[v] * logf(a[v] + 1e-8f);
        outr[bn] = 1.f - ent * 0.6213349345596119f;  // 1/ln(5)
      }
    }
    __syncthreads();
    if (it < 2) {
      float n0 = 0, n1 = 0, n2 = 0, n3 = 0;
#pragma unroll
      for (int v = 0; v < NVIEW; ++v) {
        const float av = aa[v];
        n0 = fmaf(av, pf[v][0], n0); n1 = fmaf(av, pf[v][1], n1);
        n2 = fmaf(av, pf[v][2], n2); n3 = fmaf(av, pf[v][3], n3);
      }
      cw[0] = n0; cw[1] = n1; cw[2] = n2; cw[3] = n3;
    } else {
      float r0 = 0, r1 = 0, r2 = 0, r3 = 0;
#pragma unroll
      for (int v = 0; v < NVIEW; ++v) {
        const float av = aa[v];
        uint2 p = *(const uint2*)(projb + ((size_t)v * BN_TOT + bn) * CDIM + h);
        r0 = fmaf(av, bf_lo(p.x), r0); r1 = fmaf(av, bf_hi(p.x), r1);
        r2 = fmaf(av, bf_lo(p.y), r2); r3 = fmaf(av, bf_hi(p.y), r3);
      }
      float4 of; of.x = r0; of.y = r1; of.z = r2; of.w = r3;
      *(float4*)(outc + (size_t)bn * CDIM + h) = of;
    }
  }
}

extern "C" void kernel_launch(void* const* d_in, const int* in_sizes, int n_in,
                              void* d_out, int out_size, void* d_ws, size_t ws_size,
                              hipStream_t stream) {
  (void)in_sizes; (void)n_in; (void)out_size; (void)ws_size;
  const float* x  = (const float*)d_in[0];   // [B,V,N,C] fp32
  const float* wv = (const float*)d_in[1];   // [V,C,C]
  const float* w1 = (const float*)d_in[2];   // [2C,H]
  const float* b1 = (const float*)d_in[3];   // [H]
  const float* w2 = (const float*)d_in[4];   // [H,1]
  // d_in[5] = b2: uniform shift over views -> softmax-invariant, unused.

  // workspace: 86,016,000 ushorts = 172 MB (R0's exact known-safe layout)
  unsigned short* ws   = (unsigned short*)d_ws;
  unsigned short* wvT  = ws;                             //  2,949,120  [V][d][c]
  unsigned short* w1aT = ws + 2949120;                   //    589,824
  unsigned short* w1bT = ws + 3538944;                   //    589,824
  unsigned short* xb   = ws + 4128768;                   // 24,084,480  [V,BN,C]; dead after GEMM A
  unsigned short* pw1b = ws + 4128768;                   //   (aliased onto xb)
  unsigned short* projb= ws + 28213248;                  // 24,084,480
  unsigned short* xw1b = ws + 52297728;                  // 24,084,480
  unsigned short* cb   = ws + 76382208;                  //  4,816,896
  unsigned short* cw1  = ws + 81199104;                  //  4,816,896  (end: 86,016,000)

  float* outc = (float*)d_out;                           // c [B,N,C] fp32
  float* outr = outc + SLAB;                             // r [B,N]   fp32

  k_tr<<<dim3(24, 24, 7), dim3(32, 8), 0, stream>>>(wv, w1, wvT, w1aT, w1bT);
  k_cvt_mean<<<BN_TOT, 192, 0, stream>>>(x, xb, cb);
  // GEMM A: proj_v = xb_v @ wv_v ; xw1_v = xb_v @ w1a ; cw1 = cb @ w1b
  gemm_r<0><<<1617, 512, 73728, stream>>>(xb, cb, wvT, w1aT, w1bT, projb, xw1b, cw1);
  // GEMM B: pw1b_v = proj_v @ w1b (writes over dead xb)
  gemm_r<1><<<735, 512, 73728, stream>>>(projb, nullptr, nullptr, nullptr, w1bT,
                                         pw1b, nullptr, nullptr);
  // fused routing: 3 iterations pointwise in (b,n)
  k_iter3<<<BN_TOT, 192, 0, stream>>>(xw1b, cw1, pw1b, projb, b1, w2, outc, outr);
}